// Round 1
// baseline (1879.374 us; speedup 1.0000x reference)
//
#include <hip/hip_runtime.h>
#include <math.h>

#define WF 64

__device__ __forceinline__ float wave_reduce_sum(float v) {
#pragma unroll
    for (int off = 32; off > 0; off >>= 1) v += __shfl_xor(v, off, 64);
    return v;
}

// ---------- preprocessing ----------
__global__ void k_init_deg(int* deg, int N) {
    int i = blockIdx.x * blockDim.x + threadIdx.x;
    if (i < N) deg[i] = 1;  // self loop
}

__global__ void k_count(const int* __restrict__ dst, int* deg, int E) {
    int i = blockIdx.x * blockDim.x + threadIdx.x;
    if (i < E) atomicAdd(&deg[dst[i]], 1);
}

__global__ void k_dis(const int* __restrict__ deg, float* dis, int N) {
    int i = blockIdx.x * blockDim.x + threadIdx.x;
    if (i < N) dis[i] = rsqrtf((float)deg[i]);  // deg >= 1 always
}

// exclusive scan of deg[0..N) -> offs[0..N], offs[N] = total
__global__ void k_scan1(const int* __restrict__ deg, int* part, int N) {
    int base = blockIdx.x * 1024;
    int tid = threadIdx.x;
    int s = 0;
#pragma unroll
    for (int j = 0; j < 4; ++j) {
        int idx = base + tid * 4 + j;
        if (idx < N) s += deg[idx];
    }
    __shared__ int sm[256];
    sm[tid] = s;
    __syncthreads();
    // block reduce
    for (int off = 128; off > 0; off >>= 1) {
        if (tid < off) sm[tid] += sm[tid + off];
        __syncthreads();
    }
    if (tid == 0) part[blockIdx.x] = sm[0];
}

__global__ void k_scan2(int* part, int nb, int* offs, int N) {
    if (blockIdx.x == 0 && threadIdx.x == 0) {
        int run = 0;
        for (int b = 0; b < nb; ++b) { int t = part[b]; part[b] = run; run += t; }
        offs[N] = run;
    }
}

__global__ void k_scan3(const int* __restrict__ deg, const int* __restrict__ part,
                        int* offs, int N) {
    __shared__ int sm[256];
    int base = blockIdx.x * 1024;
    int tid = threadIdx.x;
    int a[4];
    int s = 0;
#pragma unroll
    for (int j = 0; j < 4; ++j) {
        int idx = base + tid * 4 + j;
        a[j] = (idx < N) ? deg[idx] : 0;
        s += a[j];
    }
    sm[tid] = s;
    __syncthreads();
    // Hillis-Steele inclusive scan over 256 thread sums
    for (int off = 1; off < 256; off <<= 1) {
        int v = (tid >= off) ? sm[tid - off] : 0;
        __syncthreads();
        sm[tid] += v;
        __syncthreads();
    }
    int excl = sm[tid] - s + part[blockIdx.x];
#pragma unroll
    for (int j = 0; j < 4; ++j) {
        int idx = base + tid * 4 + j;
        if (idx < N) offs[idx] = excl;
        excl += a[j];
    }
}

__global__ void k_fill(const int* __restrict__ ei, int E, int N,
                       const int* __restrict__ offs, int* cursor, int* csr) {
    int i = blockIdx.x * blockDim.x + threadIdx.x;
    if (i >= E + N) return;
    int s, d;
    if (i < E) { s = ei[i]; d = ei[E + i]; }
    else { s = d = i - E; }
    int p = offs[d] + atomicAdd(&cursor[d], 1);
    csr[p] = s;
}

__global__ void k_gstart(const int* __restrict__ batch, int N, int* gstart, int G) {
    int g = blockIdx.x * blockDim.x + threadIdx.x;
    if (g > G) return;
    int lo = 0, hi = N;
    while (lo < hi) {
        int mid = (lo + hi) >> 1;
        if (batch[mid] < g) lo = mid + 1; else hi = mid;
    }
    gstart[g] = lo;
}

// ---------- GCN aggregation: agg[i] = sum_e norm_e * h[src_e] ----------
__global__ __launch_bounds__(256) void k_gcn_agg(
    const float* __restrict__ h, const int* __restrict__ csr,
    const int* __restrict__ offs, const float* __restrict__ dis,
    float* __restrict__ agg, int N)
{
    int w = (blockIdx.x * blockDim.x + threadIdx.x) >> 6;
    int lane = threadIdx.x & 63;
    if (w >= N) return;
    int j0 = offs[w], j1 = offs[w + 1];
    float dd = dis[w];
    float ax = 0.f, ay = 0.f;
    const float* hp = h + lane * 2;
    for (int j = j0; j < j1; ++j) {
        int s = csr[j];
        float wgt = dd * dis[s];
        float2 v = *(const float2*)(hp + (size_t)s * 128);
        ax += wgt * v.x;
        ay += wgt * v.y;
    }
    float2 o; o.x = ax; o.y = ay;
    *(float2*)(agg + (size_t)w * 128 + lane * 2) = o;
}

// ---------- fused out = tanh(in @ W + b), in: nrows x 128, W: 128 x 128 ----------
__global__ __launch_bounds__(256) void k_gemm_bias_tanh(
    const float* __restrict__ in, const float* __restrict__ W,
    const float* __restrict__ bias, float* __restrict__ out, int nrows)
{
    __shared__ float Wl[64][128];    // 32 KB (half of K)
    __shared__ float inT[128][36];   // transposed input tile, 18.4 KB, stride 36 keeps 16B align
    int tid = threadIdx.x;
    int row0 = blockIdx.x * 32;

    // stage input tile transposed: inT[k][r]
    for (int t = tid; t < 1024; t += 256) {
        int r = t >> 5, k4 = t & 31;
        int row = row0 + r;
        float4 v = make_float4(0.f, 0.f, 0.f, 0.f);
        if (row < nrows) v = *(const float4*)(in + (size_t)row * 128 + k4 * 4);
        inT[k4 * 4 + 0][r] = v.x;
        inT[k4 * 4 + 1][r] = v.y;
        inT[k4 * 4 + 2][r] = v.z;
        inT[k4 * 4 + 3][r] = v.w;
    }

    int cg = tid & 31;   // col group: cols cg*4 .. +3
    int rg = tid >> 5;   // row group: rows rg*4 .. +3
    float acc[4][4] = {};

    for (int kt = 0; kt < 2; ++kt) {
        __syncthreads();  // inT ready / previous Wl reads done
        for (int t = tid; t < 2048; t += 256) {
            int k = t >> 5, c4 = t & 31;
            *(float4*)&Wl[k][c4 * 4] =
                *(const float4*)(W + (size_t)(kt * 64 + k) * 128 + c4 * 4);
        }
        __syncthreads();
#pragma unroll 4
        for (int k = 0; k < 64; ++k) {
            float4 a = *(const float4*)&inT[kt * 64 + k][rg * 4];
            float4 wv = *(const float4*)&Wl[k][cg * 4];
            float av[4] = {a.x, a.y, a.z, a.w};
            float wvv[4] = {wv.x, wv.y, wv.z, wv.w};
#pragma unroll
            for (int i = 0; i < 4; ++i)
#pragma unroll
                for (int j = 0; j < 4; ++j)
                    acc[i][j] += av[i] * wvv[j];
        }
    }

    float4 bb = *(const float4*)(bias + cg * 4);
    float bv[4] = {bb.x, bb.y, bb.z, bb.w};
#pragma unroll
    for (int i = 0; i < 4; ++i) {
        int row = row0 + rg * 4 + i;
        if (row < nrows) {
            float4 o;
            o.x = tanhf(acc[i][0] + bv[0]);
            o.y = tanhf(acc[i][1] + bv[1]);
            o.z = tanhf(acc[i][2] + bv[2]);
            o.w = tanhf(acc[i][3] + bv[3]);
            *(float4*)(out + (size_t)row * 128 + cg * 4) = o;
        }
    }
}

// ---------- inverse row norm ----------
__global__ __launch_bounds__(256) void k_invnrm(
    const float* __restrict__ h, float* __restrict__ invn, int N)
{
    int w = (blockIdx.x * blockDim.x + threadIdx.x) >> 6;
    int lane = threadIdx.x & 63;
    if (w >= N) return;
    float2 v = *(const float2*)(h + (size_t)w * 128 + lane * 2);
    float s = v.x * v.x + v.y * v.y;
    s = wave_reduce_sum(s);
    if (lane == 0) invn[w] = 1.0f / fmaxf(sqrtf(s), 1e-12f);
}

// ---------- AGNN layer with online softmax, fused tanh ----------
__global__ __launch_bounds__(256) void k_agnn(
    const float* __restrict__ h, const int* __restrict__ csr,
    const int* __restrict__ offs, const float* __restrict__ invn,
    const float* __restrict__ beta_p, float* __restrict__ out, int N)
{
    int w = (blockIdx.x * blockDim.x + threadIdx.x) >> 6;
    int lane = threadIdx.x & 63;
    if (w >= N) return;
    int j0 = offs[w], j1 = offs[w + 1];
    float2 hd = *(const float2*)(h + (size_t)w * 128 + lane * 2);
    float invd = invn[w];
    float beta = beta_p[0];
    float m = -1e30f, denom = 0.f;
    float ax = 0.f, ay = 0.f;
    for (int j = j0; j < j1; ++j) {
        int s = csr[j];
        float2 hs = *(const float2*)(h + (size_t)s * 128 + lane * 2);
        float d = hs.x * hd.x + hs.y * hd.y;
        d = wave_reduce_sum(d);
        float alpha = beta * d * invd * invn[s];
        float mn = fmaxf(m, alpha);
        float sc = __expf(m - mn);
        float p = __expf(alpha - mn);
        denom = denom * sc + p;
        ax = ax * sc + p * hs.x;
        ay = ay * sc + p * hs.y;
        m = mn;
    }
    float inv = 1.0f / denom;
    float2 o;
    o.x = tanhf(ax * inv);
    o.y = tanhf(ay * inv);
    *(float2*)(out + (size_t)w * 128 + lane * 2) = o;
}

// ---------- per-graph mean pool + layernorm + final linear ----------
__global__ __launch_bounds__(256) void k_pool(
    const float* __restrict__ h, const int* __restrict__ gstart,
    const float* __restrict__ Wl, const float* __restrict__ bl,
    float* __restrict__ out, int G)
{
    int g = (blockIdx.x * blockDim.x + threadIdx.x) >> 6;
    int lane = threadIdx.x & 63;
    if (g >= G) return;
    int s = gstart[g], e = gstart[g + 1];
    float ax = 0.f, ay = 0.f;
    for (int n = s; n < e; ++n) {
        float2 v = *(const float2*)(h + (size_t)n * 128 + lane * 2);
        ax += v.x; ay += v.y;
    }
    float c = fmaxf((float)(e - s), 1.0f);
    float mx = ax / c, my = ay / c;
    float mu = wave_reduce_sum(mx + my) * (1.0f / 128.0f);
    float dx = mx - mu, dy = my - mu;
    float var = wave_reduce_sum(dx * dx + dy * dy) * (1.0f / 128.0f);
    float r = rsqrtf(var + 1e-5f);
    float2 wl = *(const float2*)(Wl + lane * 2);
    float o = wave_reduce_sum(dx * r * wl.x + dy * r * wl.y);
    if (lane == 0) out[g] = o + bl[0];
}

extern "C" void kernel_launch(void* const* d_in, const int* in_sizes, int n_in,
                              void* d_out, int out_size, void* d_ws, size_t ws_size,
                              hipStream_t stream) {
    const float* x  = (const float*)d_in[0];
    const int* ei   = (const int*)d_in[1];      // [2][E]
    const int* batch = (const int*)d_in[2];
    const float* Ws[5] = {(const float*)d_in[3], (const float*)d_in[5],
                          (const float*)d_in[7], (const float*)d_in[9],
                          (const float*)d_in[11]};
    const float* bs[5] = {(const float*)d_in[4], (const float*)d_in[6],
                          (const float*)d_in[8], (const float*)d_in[10],
                          (const float*)d_in[12]};
    const float* beta1 = (const float*)d_in[13];
    const float* beta2 = (const float*)d_in[14];
    const float* Wl = (const float*)d_in[15];
    const float* bl = (const float*)d_in[16];
    float* out = (float*)d_out;

    int N = in_sizes[0] / 128;
    int E = in_sizes[1] / 2;
    int G = out_size;

    char* ws = (char*)d_ws;
    size_t off = 0;
    auto alloc = [&](size_t bytes) -> void* {
        void* p = ws + off;
        off = (off + bytes + 255) & ~(size_t)255;
        return p;
    };
    float* bufA  = (float*)alloc((size_t)N * 128 * 4);
    float* bufB  = (float*)alloc((size_t)N * 128 * 4);
    int*   deg   = (int*)alloc((size_t)N * 4);
    int*   offs  = (int*)alloc((size_t)(N + 1) * 4);
    int*   cursor= (int*)alloc((size_t)N * 4);
    int*   csr   = (int*)alloc((size_t)(E + N) * 4);
    float* dis   = (float*)alloc((size_t)N * 4);
    float* invn  = (float*)alloc((size_t)N * 4);
    int nb = (N + 1023) / 1024;
    int*   part  = (int*)alloc((size_t)nb * 4);
    int*   gst   = (int*)alloc((size_t)(G + 1) * 4);

    // CSR build
    k_init_deg<<<(N + 255) / 256, 256, 0, stream>>>(deg, N);
    k_count<<<(E + 255) / 256, 256, 0, stream>>>(ei + E, deg, E);
    k_dis<<<(N + 255) / 256, 256, 0, stream>>>(deg, dis, N);
    k_scan1<<<nb, 256, 0, stream>>>(deg, part, N);
    k_scan2<<<1, 64, 0, stream>>>(part, nb, offs, N);
    k_scan3<<<nb, 256, 0, stream>>>(deg, part, offs, N);
    hipMemsetAsync(cursor, 0, (size_t)N * 4, stream);
    k_fill<<<(E + N + 255) / 256, 256, 0, stream>>>(ei, E, N, offs, cursor, csr);
    k_gstart<<<(G + 1 + 255) / 256, 256, 0, stream>>>(batch, N, gst, G);

    int aggBlocks = (N + 3) / 4;     // 4 waves (nodes) per 256-thread block
    int gemmBlocks = (N + 31) / 32;

    // 5 GCN layers: agg(h) -> bufA, tanh(bufA@W+b) -> bufB
    const float* hin = x;
    for (int l = 0; l < 5; ++l) {
        k_gcn_agg<<<aggBlocks, 256, 0, stream>>>(hin, csr, offs, dis, bufA, N);
        k_gemm_bias_tanh<<<gemmBlocks, 256, 0, stream>>>(bufA, Ws[l], bs[l], bufB, N);
        hin = bufB;
    }
    // AGNN x2
    k_invnrm<<<aggBlocks, 256, 0, stream>>>(bufB, invn, N);
    k_agnn<<<aggBlocks, 256, 0, stream>>>(bufB, csr, offs, invn, beta1, bufA, N);
    k_invnrm<<<aggBlocks, 256, 0, stream>>>(bufA, invn, N);
    k_agnn<<<aggBlocks, 256, 0, stream>>>(bufA, csr, offs, invn, beta2, bufB, N);
    // pool + LN + linear
    k_pool<<<(G + 3) / 4, 256, 0, stream>>>(bufB, gst, Wl, bl, out, G);
}

// Round 2
// 1402.383 us; speedup vs baseline: 1.3401x; 1.3401x over previous
//
#include <hip/hip_runtime.h>
#include <math.h>

#define WF 64

__device__ __forceinline__ float wave_reduce_sum(float v) {
#pragma unroll
    for (int off = 32; off > 0; off >>= 1) v += __shfl_xor(v, off, 64);
    return v;
}

// ---------- preprocessing ----------
__global__ void k_init_deg(int* deg, int N) {
    int i = blockIdx.x * blockDim.x + threadIdx.x;
    if (i < N) deg[i] = 1;  // self loop
}

__global__ void k_count(const int* __restrict__ dst, int* deg, int E) {
    int i = blockIdx.x * blockDim.x + threadIdx.x;
    if (i < E) atomicAdd(&deg[dst[i]], 1);
}

__global__ void k_dis(const int* __restrict__ deg, float* dis, int N) {
    int i = blockIdx.x * blockDim.x + threadIdx.x;
    if (i < N) dis[i] = rsqrtf((float)deg[i]);  // deg >= 1 always
}

// exclusive scan of deg[0..N) -> offs[0..N], offs[N] = total
__global__ void k_scan1(const int* __restrict__ deg, int* part, int N) {
    int base = blockIdx.x * 1024;
    int tid = threadIdx.x;
    int s = 0;
#pragma unroll
    for (int j = 0; j < 4; ++j) {
        int idx = base + tid * 4 + j;
        if (idx < N) s += deg[idx];
    }
    __shared__ int sm[256];
    sm[tid] = s;
    __syncthreads();
    for (int off = 128; off > 0; off >>= 1) {
        if (tid < off) sm[tid] += sm[tid + off];
        __syncthreads();
    }
    if (tid == 0) part[blockIdx.x] = sm[0];
}

__global__ void k_scan2(int* part, int nb, int* offs, int N) {
    if (blockIdx.x == 0 && threadIdx.x == 0) {
        int run = 0;
        for (int b = 0; b < nb; ++b) { int t = part[b]; part[b] = run; run += t; }
        offs[N] = run;
    }
}

__global__ void k_scan3(const int* __restrict__ deg, const int* __restrict__ part,
                        int* offs, int N) {
    __shared__ int sm[256];
    int base = blockIdx.x * 1024;
    int tid = threadIdx.x;
    int a[4];
    int s = 0;
#pragma unroll
    for (int j = 0; j < 4; ++j) {
        int idx = base + tid * 4 + j;
        a[j] = (idx < N) ? deg[idx] : 0;
        s += a[j];
    }
    sm[tid] = s;
    __syncthreads();
    for (int off = 1; off < 256; off <<= 1) {
        int v = (tid >= off) ? sm[tid - off] : 0;
        __syncthreads();
        sm[tid] += v;
        __syncthreads();
    }
    int excl = sm[tid] - s + part[blockIdx.x];
#pragma unroll
    for (int j = 0; j < 4; ++j) {
        int idx = base + tid * 4 + j;
        if (idx < N) offs[idx] = excl;
        excl += a[j];
    }
}

__global__ void k_fill(const int* __restrict__ ei, int E, int N,
                       const int* __restrict__ offs, int* cursor, int* csr) {
    int i = blockIdx.x * blockDim.x + threadIdx.x;
    if (i >= E + N) return;
    int s, d;
    if (i < E) { s = ei[i]; d = ei[E + i]; }
    else { s = d = i - E; }
    int p = offs[d] + atomicAdd(&cursor[d], 1);
    csr[p] = s;
}

__global__ void k_gstart(const int* __restrict__ batch, int N, int* gstart, int G) {
    int g = blockIdx.x * blockDim.x + threadIdx.x;
    if (g > G) return;
    int lo = 0, hi = N;
    while (lo < hi) {
        int mid = (lo + hi) >> 1;
        if (batch[mid] < g) lo = mid + 1; else hi = mid;
    }
    gstart[g] = lo;
}

// ---------- GCN aggregation: agg[i] = dis[i] * sum_e dis[src_e] * h[src_e] ----------
__global__ __launch_bounds__(256) void k_gcn_agg(
    const float* __restrict__ h, const int* __restrict__ csr,
    const int* __restrict__ offs, const float* __restrict__ dis,
    float* __restrict__ agg, int N)
{
    int w = (blockIdx.x * blockDim.x + threadIdx.x) >> 6;
    int lane = threadIdx.x & 63;
    if (w >= N) return;
    int j0 = offs[w], j1 = offs[w + 1];
    float dd = dis[w];
    float ax = 0.f, ay = 0.f;
    const float* hp = h + lane * 2;
    int j = j0;
    // 8-deep software pipeline: 8 row-gathers in flight per iteration
    for (; j + 8 <= j1; j += 8) {
        int s0 = csr[j + 0], s1 = csr[j + 1], s2 = csr[j + 2], s3 = csr[j + 3];
        int s4 = csr[j + 4], s5 = csr[j + 5], s6 = csr[j + 6], s7 = csr[j + 7];
        float w0 = dis[s0], w1 = dis[s1], w2 = dis[s2], w3 = dis[s3];
        float w4 = dis[s4], w5 = dis[s5], w6 = dis[s6], w7 = dis[s7];
        float2 v0 = *(const float2*)(hp + (size_t)s0 * 128);
        float2 v1 = *(const float2*)(hp + (size_t)s1 * 128);
        float2 v2 = *(const float2*)(hp + (size_t)s2 * 128);
        float2 v3 = *(const float2*)(hp + (size_t)s3 * 128);
        float2 v4 = *(const float2*)(hp + (size_t)s4 * 128);
        float2 v5 = *(const float2*)(hp + (size_t)s5 * 128);
        float2 v6 = *(const float2*)(hp + (size_t)s6 * 128);
        float2 v7 = *(const float2*)(hp + (size_t)s7 * 128);
        ax += w0 * v0.x + w1 * v1.x + w2 * v2.x + w3 * v3.x
            + w4 * v4.x + w5 * v5.x + w6 * v6.x + w7 * v7.x;
        ay += w0 * v0.y + w1 * v1.y + w2 * v2.y + w3 * v3.y
            + w4 * v4.y + w5 * v5.y + w6 * v6.y + w7 * v7.y;
    }
    for (; j + 4 <= j1; j += 4) {
        int s0 = csr[j + 0], s1 = csr[j + 1], s2 = csr[j + 2], s3 = csr[j + 3];
        float w0 = dis[s0], w1 = dis[s1], w2 = dis[s2], w3 = dis[s3];
        float2 v0 = *(const float2*)(hp + (size_t)s0 * 128);
        float2 v1 = *(const float2*)(hp + (size_t)s1 * 128);
        float2 v2 = *(const float2*)(hp + (size_t)s2 * 128);
        float2 v3 = *(const float2*)(hp + (size_t)s3 * 128);
        ax += w0 * v0.x + w1 * v1.x + w2 * v2.x + w3 * v3.x;
        ay += w0 * v0.y + w1 * v1.y + w2 * v2.y + w3 * v3.y;
    }
    for (; j < j1; ++j) {
        int s = csr[j];
        float ws = dis[s];
        float2 v = *(const float2*)(hp + (size_t)s * 128);
        ax += ws * v.x; ay += ws * v.y;
    }
    *(float2*)(agg + (size_t)w * 128 + lane * 2) = make_float2(dd * ax, dd * ay);
}

// ---------- fused out = tanh(in @ W + b); optional inverse-row-norm epilogue ----------
__global__ __launch_bounds__(256) void k_gemm_bias_tanh(
    const float* __restrict__ in, const float* __restrict__ W,
    const float* __restrict__ bias, float* __restrict__ out, int nrows,
    float* __restrict__ invn_out)
{
    __shared__ float Wl[64][128];    // 32 KB (half of K)
    __shared__ float inT[128][36];   // transposed input tile, stride 36 keeps 16B align
    int tid = threadIdx.x;
    int row0 = blockIdx.x * 32;

    for (int t = tid; t < 1024; t += 256) {
        int r = t >> 5, k4 = t & 31;
        int row = row0 + r;
        float4 v = make_float4(0.f, 0.f, 0.f, 0.f);
        if (row < nrows) v = *(const float4*)(in + (size_t)row * 128 + k4 * 4);
        inT[k4 * 4 + 0][r] = v.x;
        inT[k4 * 4 + 1][r] = v.y;
        inT[k4 * 4 + 2][r] = v.z;
        inT[k4 * 4 + 3][r] = v.w;
    }

    int cg = tid & 31;   // col group
    int rg = tid >> 5;   // row group
    float acc[4][4] = {};

    for (int kt = 0; kt < 2; ++kt) {
        __syncthreads();
        for (int t = tid; t < 2048; t += 256) {
            int k = t >> 5, c4 = t & 31;
            *(float4*)&Wl[k][c4 * 4] =
                *(const float4*)(W + (size_t)(kt * 64 + k) * 128 + c4 * 4);
        }
        __syncthreads();
#pragma unroll 4
        for (int k = 0; k < 64; ++k) {
            float4 a = *(const float4*)&inT[kt * 64 + k][rg * 4];
            float4 wv = *(const float4*)&Wl[k][cg * 4];
            float av[4] = {a.x, a.y, a.z, a.w};
            float wvv[4] = {wv.x, wv.y, wv.z, wv.w};
#pragma unroll
            for (int i = 0; i < 4; ++i)
#pragma unroll
                for (int j = 0; j < 4; ++j)
                    acc[i][j] += av[i] * wvv[j];
        }
    }

    float4 bb = *(const float4*)(bias + cg * 4);
    float bv[4] = {bb.x, bb.y, bb.z, bb.w};
    float sq[4];
#pragma unroll
    for (int i = 0; i < 4; ++i) {
        int row = row0 + rg * 4 + i;
        float4 o;
        o.x = tanhf(acc[i][0] + bv[0]);
        o.y = tanhf(acc[i][1] + bv[1]);
        o.z = tanhf(acc[i][2] + bv[2]);
        o.w = tanhf(acc[i][3] + bv[3]);
        sq[i] = o.x * o.x + o.y * o.y + o.z * o.z + o.w * o.w;
        if (row < nrows)
            *(float4*)(out + (size_t)row * 128 + cg * 4) = o;
    }
    if (invn_out) {
        // reduce sq across the 32 lanes sharing this rg (contiguous half-wave)
#pragma unroll
        for (int i = 0; i < 4; ++i) {
#pragma unroll
            for (int off = 16; off > 0; off >>= 1) sq[i] += __shfl_xor(sq[i], off, 64);
            int row = row0 + rg * 4 + i;
            if (cg == 0 && row < nrows)
                invn_out[row] = 1.0f / fmaxf(sqrtf(sq[i]), 1e-12f);
        }
    }
}

// ---------- AGNN layer: shift-free softmax (alpha bounded by |beta|), fused tanh,
// ---------- optional inverse-norm epilogue for the next AGNN layer ----------
__global__ __launch_bounds__(256) void k_agnn(
    const float* __restrict__ h, const int* __restrict__ csr,
    const int* __restrict__ offs, const float* __restrict__ invn,
    const float* __restrict__ beta_p, float* __restrict__ out, int N,
    float* __restrict__ invn_out)
{
    int w = (blockIdx.x * blockDim.x + threadIdx.x) >> 6;
    int lane = threadIdx.x & 63;
    if (w >= N) return;
    int j0 = offs[w], j1 = offs[w + 1];
    float2 hd = *(const float2*)(h + (size_t)w * 128 + lane * 2);
    float bi = beta_p[0] * invn[w];
    float denom = 0.f, ax = 0.f, ay = 0.f;
    int j = j0;
    for (; j + 4 <= j1; j += 4) {
        int s0 = csr[j + 0], s1 = csr[j + 1], s2 = csr[j + 2], s3 = csr[j + 3];
        float in0 = invn[s0], in1 = invn[s1], in2 = invn[s2], in3 = invn[s3];
        float2 v0 = *(const float2*)(h + (size_t)s0 * 128 + lane * 2);
        float2 v1 = *(const float2*)(h + (size_t)s1 * 128 + lane * 2);
        float2 v2 = *(const float2*)(h + (size_t)s2 * 128 + lane * 2);
        float2 v3 = *(const float2*)(h + (size_t)s3 * 128 + lane * 2);
        float d0 = v0.x * hd.x + v0.y * hd.y;
        float d1 = v1.x * hd.x + v1.y * hd.y;
        float d2 = v2.x * hd.x + v2.y * hd.y;
        float d3 = v3.x * hd.x + v3.y * hd.y;
#pragma unroll
        for (int off = 32; off > 0; off >>= 1) {
            d0 += __shfl_xor(d0, off, 64);
            d1 += __shfl_xor(d1, off, 64);
            d2 += __shfl_xor(d2, off, 64);
            d3 += __shfl_xor(d3, off, 64);
        }
        float p0 = __expf(bi * in0 * d0);
        float p1 = __expf(bi * in1 * d1);
        float p2 = __expf(bi * in2 * d2);
        float p3 = __expf(bi * in3 * d3);
        denom += p0 + p1 + p2 + p3;
        ax += p0 * v0.x + p1 * v1.x + p2 * v2.x + p3 * v3.x;
        ay += p0 * v0.y + p1 * v1.y + p2 * v2.y + p3 * v3.y;
    }
    for (; j < j1; ++j) {
        int s = csr[j];
        float ins = invn[s];
        float2 vs = *(const float2*)(h + (size_t)s * 128 + lane * 2);
        float d = vs.x * hd.x + vs.y * hd.y;
        d = wave_reduce_sum(d);
        float p = __expf(bi * ins * d);
        denom += p;
        ax += p * vs.x;
        ay += p * vs.y;
    }
    float inv = 1.0f / denom;
    float2 o;
    o.x = tanhf(ax * inv);
    o.y = tanhf(ay * inv);
    *(float2*)(out + (size_t)w * 128 + lane * 2) = o;
    if (invn_out) {
        float s2 = o.x * o.x + o.y * o.y;
        s2 = wave_reduce_sum(s2);
        if (lane == 0) invn_out[w] = 1.0f / fmaxf(sqrtf(s2), 1e-12f);
    }
}

// ---------- per-graph mean pool + layernorm + final linear ----------
__global__ __launch_bounds__(256) void k_pool(
    const float* __restrict__ h, const int* __restrict__ gstart,
    const float* __restrict__ Wl, const float* __restrict__ bl,
    float* __restrict__ out, int G)
{
    int g = (blockIdx.x * blockDim.x + threadIdx.x) >> 6;
    int lane = threadIdx.x & 63;
    if (g >= G) return;
    int s = gstart[g], e = gstart[g + 1];
    float ax = 0.f, ay = 0.f;
    int n = s;
    for (; n + 4 <= e; n += 4) {
        float2 v0 = *(const float2*)(h + (size_t)(n + 0) * 128 + lane * 2);
        float2 v1 = *(const float2*)(h + (size_t)(n + 1) * 128 + lane * 2);
        float2 v2 = *(const float2*)(h + (size_t)(n + 2) * 128 + lane * 2);
        float2 v3 = *(const float2*)(h + (size_t)(n + 3) * 128 + lane * 2);
        ax += v0.x + v1.x + v2.x + v3.x;
        ay += v0.y + v1.y + v2.y + v3.y;
    }
    for (; n < e; ++n) {
        float2 v = *(const float2*)(h + (size_t)n * 128 + lane * 2);
        ax += v.x; ay += v.y;
    }
    float c = fmaxf((float)(e - s), 1.0f);
    float mx = ax / c, my = ay / c;
    float mu = wave_reduce_sum(mx + my) * (1.0f / 128.0f);
    float dx = mx - mu, dy = my - mu;
    float var = wave_reduce_sum(dx * dx + dy * dy) * (1.0f / 128.0f);
    float r = rsqrtf(var + 1e-5f);
    float2 wl = *(const float2*)(Wl + lane * 2);
    float o = wave_reduce_sum(dx * r * wl.x + dy * r * wl.y);
    if (lane == 0) out[g] = o + bl[0];
}

extern "C" void kernel_launch(void* const* d_in, const int* in_sizes, int n_in,
                              void* d_out, int out_size, void* d_ws, size_t ws_size,
                              hipStream_t stream) {
    const float* x  = (const float*)d_in[0];
    const int* ei   = (const int*)d_in[1];      // [2][E]
    const int* batch = (const int*)d_in[2];
    const float* Ws[5] = {(const float*)d_in[3], (const float*)d_in[5],
                          (const float*)d_in[7], (const float*)d_in[9],
                          (const float*)d_in[11]};
    const float* bs[5] = {(const float*)d_in[4], (const float*)d_in[6],
                          (const float*)d_in[8], (const float*)d_in[10],
                          (const float*)d_in[12]};
    const float* beta1 = (const float*)d_in[13];
    const float* beta2 = (const float*)d_in[14];
    const float* Wl = (const float*)d_in[15];
    const float* bl = (const float*)d_in[16];
    float* out = (float*)d_out;

    int N = in_sizes[0] / 128;
    int E = in_sizes[1] / 2;
    int G = out_size;

    char* ws = (char*)d_ws;
    size_t off = 0;
    auto alloc = [&](size_t bytes) -> void* {
        void* p = ws + off;
        off = (off + bytes + 255) & ~(size_t)255;
        return p;
    };
    float* bufA  = (float*)alloc((size_t)N * 128 * 4);
    float* bufB  = (float*)alloc((size_t)N * 128 * 4);
    int*   deg   = (int*)alloc((size_t)N * 4);
    int*   offs  = (int*)alloc((size_t)(N + 1) * 4);
    int*   cursor= (int*)alloc((size_t)N * 4);
    int*   csr   = (int*)alloc((size_t)(E + N) * 4);
    float* dis   = (float*)alloc((size_t)N * 4);
    float* invn  = (float*)alloc((size_t)N * 4);
    float* invn2 = (float*)alloc((size_t)N * 4);
    int nb = (N + 1023) / 1024;
    int*   part  = (int*)alloc((size_t)nb * 4);
    int*   gst   = (int*)alloc((size_t)(G + 1) * 4);

    // CSR build
    k_init_deg<<<(N + 255) / 256, 256, 0, stream>>>(deg, N);
    k_count<<<(E + 255) / 256, 256, 0, stream>>>(ei + E, deg, E);
    k_dis<<<(N + 255) / 256, 256, 0, stream>>>(deg, dis, N);
    k_scan1<<<nb, 256, 0, stream>>>(deg, part, N);
    k_scan2<<<1, 64, 0, stream>>>(part, nb, offs, N);
    k_scan3<<<nb, 256, 0, stream>>>(deg, part, offs, N);
    hipMemsetAsync(cursor, 0, (size_t)N * 4, stream);
    k_fill<<<(E + N + 255) / 256, 256, 0, stream>>>(ei, E, N, offs, cursor, csr);
    k_gstart<<<(G + 1 + 255) / 256, 256, 0, stream>>>(batch, N, gst, G);

    int aggBlocks = (N + 3) / 4;     // 4 waves (nodes) per 256-thread block
    int gemmBlocks = (N + 31) / 32;

    // 5 GCN layers; layer 5's GEMM epilogue also produces invn of its output
    const float* hin = x;
    for (int l = 0; l < 5; ++l) {
        k_gcn_agg<<<aggBlocks, 256, 0, stream>>>(hin, csr, offs, dis, bufA, N);
        k_gemm_bias_tanh<<<gemmBlocks, 256, 0, stream>>>(
            bufA, Ws[l], bs[l], bufB, N, (l == 4) ? invn : nullptr);
        hin = bufB;
    }
    // AGNN x2 (first writes invn2 of its output for the second)
    k_agnn<<<aggBlocks, 256, 0, stream>>>(bufB, csr, offs, invn, beta1, bufA, N, invn2);
    k_agnn<<<aggBlocks, 256, 0, stream>>>(bufA, csr, offs, invn2, beta2, bufB, N, nullptr);
    // pool + LN + linear
    k_pool<<<(G + 3) / 4, 256, 0, stream>>>(bufB, gst, Wl, bl, out, G);
}

// Round 3
// 1099.052 us; speedup vs baseline: 1.7100x; 1.2760x over previous
//
#include <hip/hip_runtime.h>
#include <hip/hip_fp16.h>
#include <math.h>

#define WF 64

__device__ __forceinline__ float wave_reduce_sum(float v) {
#pragma unroll
    for (int off = 32; off > 0; off >>= 1) v += __shfl_xor(v, off, 64);
    return v;
}

// ---------- preprocessing ----------
__global__ void k_init_deg(int* deg, int N) {
    int i = blockIdx.x * blockDim.x + threadIdx.x;
    if (i < N) deg[i] = 1;  // self loop
}

__global__ void k_count(const int* __restrict__ dst, int* deg, int E) {
    int i = blockIdx.x * blockDim.x + threadIdx.x;
    if (i < E) atomicAdd(&deg[dst[i]], 1);
}

__global__ void k_dis(const int* __restrict__ deg, float* dis, int N) {
    int i = blockIdx.x * blockDim.x + threadIdx.x;
    if (i < N) dis[i] = rsqrtf((float)deg[i]);  // deg >= 1 always
}

// exclusive scan of deg[0..N) -> offs[0..N], offs[N] = total
__global__ void k_scan1(const int* __restrict__ deg, int* part, int N) {
    int base = blockIdx.x * 1024;
    int tid = threadIdx.x;
    int s = 0;
#pragma unroll
    for (int j = 0; j < 4; ++j) {
        int idx = base + tid * 4 + j;
        if (idx < N) s += deg[idx];
    }
    __shared__ int sm[256];
    sm[tid] = s;
    __syncthreads();
    for (int off = 128; off > 0; off >>= 1) {
        if (tid < off) sm[tid] += sm[tid + off];
        __syncthreads();
    }
    if (tid == 0) part[blockIdx.x] = sm[0];
}

__global__ void k_scan2(int* part, int nb, int* offs, int N) {
    if (blockIdx.x == 0 && threadIdx.x == 0) {
        int run = 0;
        for (int b = 0; b < nb; ++b) { int t = part[b]; part[b] = run; run += t; }
        offs[N] = run;
    }
}

__global__ void k_scan3(const int* __restrict__ deg, const int* __restrict__ part,
                        int* offs, int N) {
    __shared__ int sm[256];
    int base = blockIdx.x * 1024;
    int tid = threadIdx.x;
    int a[4];
    int s = 0;
#pragma unroll
    for (int j = 0; j < 4; ++j) {
        int idx = base + tid * 4 + j;
        a[j] = (idx < N) ? deg[idx] : 0;
        s += a[j];
    }
    sm[tid] = s;
    __syncthreads();
    for (int off = 1; off < 256; off <<= 1) {
        int v = (tid >= off) ? sm[tid - off] : 0;
        __syncthreads();
        sm[tid] += v;
        __syncthreads();
    }
    int excl = sm[tid] - s + part[blockIdx.x];
#pragma unroll
    for (int j = 0; j < 4; ++j) {
        int idx = base + tid * 4 + j;
        if (idx < N) offs[idx] = excl;
        excl += a[j];
    }
}

__global__ void k_fill(const int* __restrict__ ei, int E, int N,
                       const int* __restrict__ offs, int* cursor, int* csr) {
    int i = blockIdx.x * blockDim.x + threadIdx.x;
    if (i >= E + N) return;
    int s, d;
    if (i < E) { s = ei[i]; d = ei[E + i]; }
    else { s = d = i - E; }
    int p = offs[d] + atomicAdd(&cursor[d], 1);
    csr[p] = s;
}

__global__ void k_gstart(const int* __restrict__ batch, int N, int* gstart, int G) {
    int g = blockIdx.x * blockDim.x + threadIdx.x;
    if (g > G) return;
    int lo = 0, hi = N;
    while (lo < hi) {
        int mid = (lo + hi) >> 1;
        if (batch[mid] < g) lo = mid + 1; else hi = mid;
    }
    gstart[g] = lo;
}

// ---------- f32 -> fp16 cast (x pre-pass) ----------
__global__ __launch_bounds__(256) void k_cast(
    const float* __restrict__ x, __half* __restrict__ hx, int npairs)
{
    int i = blockIdx.x * blockDim.x + threadIdx.x;
    if (i >= npairs) return;
    float2 v = ((const float2*)x)[i];
    ((__half2*)hx)[i] = __floats2half2_rn(v.x, v.y);
}

// ---------- GCN aggregation (fp16 gather): agg[i] = dis[i]*sum dis[s]*h[s] ----------
__global__ __launch_bounds__(256) void k_gcn_agg(
    const __half* __restrict__ h, const int* __restrict__ csr,
    const int* __restrict__ offs, const float* __restrict__ dis,
    float* __restrict__ agg, int N)
{
    int w = (blockIdx.x * blockDim.x + threadIdx.x) >> 6;
    int lane = threadIdx.x & 63;
    if (w >= N) return;
    int j0 = offs[w], j1 = offs[w + 1];
    float dd = dis[w];
    float ax = 0.f, ay = 0.f;
    const __half2* hp = (const __half2*)h + lane;   // row stride = 64 half2
    int j = j0;
    for (; j + 8 <= j1; j += 8) {
        int s0 = csr[j + 0], s1 = csr[j + 1], s2 = csr[j + 2], s3 = csr[j + 3];
        int s4 = csr[j + 4], s5 = csr[j + 5], s6 = csr[j + 6], s7 = csr[j + 7];
        float w0 = dis[s0], w1 = dis[s1], w2 = dis[s2], w3 = dis[s3];
        float w4 = dis[s4], w5 = dis[s5], w6 = dis[s6], w7 = dis[s7];
        float2 v0 = __half22float2(hp[(size_t)s0 * 64]);
        float2 v1 = __half22float2(hp[(size_t)s1 * 64]);
        float2 v2 = __half22float2(hp[(size_t)s2 * 64]);
        float2 v3 = __half22float2(hp[(size_t)s3 * 64]);
        float2 v4 = __half22float2(hp[(size_t)s4 * 64]);
        float2 v5 = __half22float2(hp[(size_t)s5 * 64]);
        float2 v6 = __half22float2(hp[(size_t)s6 * 64]);
        float2 v7 = __half22float2(hp[(size_t)s7 * 64]);
        ax += w0 * v0.x + w1 * v1.x + w2 * v2.x + w3 * v3.x
            + w4 * v4.x + w5 * v5.x + w6 * v6.x + w7 * v7.x;
        ay += w0 * v0.y + w1 * v1.y + w2 * v2.y + w3 * v3.y
            + w4 * v4.y + w5 * v5.y + w6 * v6.y + w7 * v7.y;
    }
    for (; j + 4 <= j1; j += 4) {
        int s0 = csr[j + 0], s1 = csr[j + 1], s2 = csr[j + 2], s3 = csr[j + 3];
        float w0 = dis[s0], w1 = dis[s1], w2 = dis[s2], w3 = dis[s3];
        float2 v0 = __half22float2(hp[(size_t)s0 * 64]);
        float2 v1 = __half22float2(hp[(size_t)s1 * 64]);
        float2 v2 = __half22float2(hp[(size_t)s2 * 64]);
        float2 v3 = __half22float2(hp[(size_t)s3 * 64]);
        ax += w0 * v0.x + w1 * v1.x + w2 * v2.x + w3 * v3.x;
        ay += w0 * v0.y + w1 * v1.y + w2 * v2.y + w3 * v3.y;
    }
    for (; j < j1; ++j) {
        int s = csr[j];
        float ws = dis[s];
        float2 v = __half22float2(hp[(size_t)s * 64]);
        ax += ws * v.x; ay += ws * v.y;
    }
    *(float2*)(agg + (size_t)w * 128 + lane * 2) = make_float2(dd * ax, dd * ay);
}

// ---------- fused out(fp16) = tanh(in @ W + b); optional invnorm epilogue ----------
__global__ __launch_bounds__(256) void k_gemm_bias_tanh(
    const float* __restrict__ in, const float* __restrict__ W,
    const float* __restrict__ bias, __half* __restrict__ out, int nrows,
    float* __restrict__ invn_out)
{
    __shared__ float Wl[64][128];
    __shared__ float inT[128][36];
    int tid = threadIdx.x;
    int row0 = blockIdx.x * 32;

    for (int t = tid; t < 1024; t += 256) {
        int r = t >> 5, k4 = t & 31;
        int row = row0 + r;
        float4 v = make_float4(0.f, 0.f, 0.f, 0.f);
        if (row < nrows) v = *(const float4*)(in + (size_t)row * 128 + k4 * 4);
        inT[k4 * 4 + 0][r] = v.x;
        inT[k4 * 4 + 1][r] = v.y;
        inT[k4 * 4 + 2][r] = v.z;
        inT[k4 * 4 + 3][r] = v.w;
    }

    int cg = tid & 31;
    int rg = tid >> 5;
    float acc[4][4] = {};

    for (int kt = 0; kt < 2; ++kt) {
        __syncthreads();
        for (int t = tid; t < 2048; t += 256) {
            int k = t >> 5, c4 = t & 31;
            *(float4*)&Wl[k][c4 * 4] =
                *(const float4*)(W + (size_t)(kt * 64 + k) * 128 + c4 * 4);
        }
        __syncthreads();
#pragma unroll 4
        for (int k = 0; k < 64; ++k) {
            float4 a = *(const float4*)&inT[kt * 64 + k][rg * 4];
            float4 wv = *(const float4*)&Wl[k][cg * 4];
            float av[4] = {a.x, a.y, a.z, a.w};
            float wvv[4] = {wv.x, wv.y, wv.z, wv.w};
#pragma unroll
            for (int i = 0; i < 4; ++i)
#pragma unroll
                for (int j = 0; j < 4; ++j)
                    acc[i][j] += av[i] * wvv[j];
        }
    }

    float4 bb = *(const float4*)(bias + cg * 4);
    float bv[4] = {bb.x, bb.y, bb.z, bb.w};
    float sq[4];
#pragma unroll
    for (int i = 0; i < 4; ++i) {
        int row = row0 + rg * 4 + i;
        float ox = tanhf(acc[i][0] + bv[0]);
        float oy = tanhf(acc[i][1] + bv[1]);
        float oz = tanhf(acc[i][2] + bv[2]);
        float ow = tanhf(acc[i][3] + bv[3]);
        sq[i] = ox * ox + oy * oy + oz * oz + ow * ow;
        if (row < nrows) {
            union { __half2 h[2]; uint2 u; } pk;
            pk.h[0] = __floats2half2_rn(ox, oy);
            pk.h[1] = __floats2half2_rn(oz, ow);
            *(uint2*)(out + (size_t)row * 128 + cg * 4) = pk.u;
        }
    }
    if (invn_out) {
#pragma unroll
        for (int i = 0; i < 4; ++i) {
#pragma unroll
            for (int off = 16; off > 0; off >>= 1) sq[i] += __shfl_xor(sq[i], off, 64);
            int row = row0 + rg * 4 + i;
            if (cg == 0 && row < nrows)
                invn_out[row] = 1.0f / fmaxf(sqrtf(sq[i]), 1e-12f);
        }
    }
}

// ---------- AGNN layer (fp16 gather, shift-free softmax, fused tanh) ----------
__global__ __launch_bounds__(256) void k_agnn(
    const __half* __restrict__ h, const int* __restrict__ csr,
    const int* __restrict__ offs, const float* __restrict__ invn,
    const float* __restrict__ beta_p, __half* __restrict__ out, int N,
    float* __restrict__ invn_out)
{
    int w = (blockIdx.x * blockDim.x + threadIdx.x) >> 6;
    int lane = threadIdx.x & 63;
    if (w >= N) return;
    int j0 = offs[w], j1 = offs[w + 1];
    const __half2* hp = (const __half2*)h + lane;   // row stride = 64 half2
    float2 hd = __half22float2(hp[(size_t)w * 64]);
    float bi = beta_p[0] * invn[w];
    float denom = 0.f, ax = 0.f, ay = 0.f;
    int j = j0;
    for (; j + 4 <= j1; j += 4) {
        int s0 = csr[j + 0], s1 = csr[j + 1], s2 = csr[j + 2], s3 = csr[j + 3];
        float in0 = invn[s0], in1 = invn[s1], in2 = invn[s2], in3 = invn[s3];
        float2 v0 = __half22float2(hp[(size_t)s0 * 64]);
        float2 v1 = __half22float2(hp[(size_t)s1 * 64]);
        float2 v2 = __half22float2(hp[(size_t)s2 * 64]);
        float2 v3 = __half22float2(hp[(size_t)s3 * 64]);
        float d0 = v0.x * hd.x + v0.y * hd.y;
        float d1 = v1.x * hd.x + v1.y * hd.y;
        float d2 = v2.x * hd.x + v2.y * hd.y;
        float d3 = v3.x * hd.x + v3.y * hd.y;
#pragma unroll
        for (int off = 32; off > 0; off >>= 1) {
            d0 += __shfl_xor(d0, off, 64);
            d1 += __shfl_xor(d1, off, 64);
            d2 += __shfl_xor(d2, off, 64);
            d3 += __shfl_xor(d3, off, 64);
        }
        float p0 = __expf(bi * in0 * d0);
        float p1 = __expf(bi * in1 * d1);
        float p2 = __expf(bi * in2 * d2);
        float p3 = __expf(bi * in3 * d3);
        denom += p0 + p1 + p2 + p3;
        ax += p0 * v0.x + p1 * v1.x + p2 * v2.x + p3 * v3.x;
        ay += p0 * v0.y + p1 * v1.y + p2 * v2.y + p3 * v3.y;
    }
    for (; j < j1; ++j) {
        int s = csr[j];
        float ins = invn[s];
        float2 vs = __half22float2(hp[(size_t)s * 64]);
        float d = vs.x * hd.x + vs.y * hd.y;
        d = wave_reduce_sum(d);
        float p = __expf(bi * ins * d);
        denom += p;
        ax += p * vs.x;
        ay += p * vs.y;
    }
    float inv = 1.0f / denom;
    float ox = tanhf(ax * inv);
    float oy = tanhf(ay * inv);
    ((__half2*)out)[(size_t)w * 64 + lane] = __floats2half2_rn(ox, oy);
    if (invn_out) {
        float s2 = ox * ox + oy * oy;
        s2 = wave_reduce_sum(s2);
        if (lane == 0) invn_out[w] = 1.0f / fmaxf(sqrtf(s2), 1e-12f);
    }
}

// ---------- per-graph mean pool + layernorm + final linear ----------
__global__ __launch_bounds__(256) void k_pool(
    const __half* __restrict__ h, const int* __restrict__ gstart,
    const float* __restrict__ Wl, const float* __restrict__ bl,
    float* __restrict__ out, int G)
{
    int g = (blockIdx.x * blockDim.x + threadIdx.x) >> 6;
    int lane = threadIdx.x & 63;
    if (g >= G) return;
    int s = gstart[g], e = gstart[g + 1];
    const __half2* hp = (const __half2*)h + lane;
    float ax = 0.f, ay = 0.f;
    int n = s;
    for (; n + 4 <= e; n += 4) {
        float2 v0 = __half22float2(hp[(size_t)(n + 0) * 64]);
        float2 v1 = __half22float2(hp[(size_t)(n + 1) * 64]);
        float2 v2 = __half22float2(hp[(size_t)(n + 2) * 64]);
        float2 v3 = __half22float2(hp[(size_t)(n + 3) * 64]);
        ax += v0.x + v1.x + v2.x + v3.x;
        ay += v0.y + v1.y + v2.y + v3.y;
    }
    for (; n < e; ++n) {
        float2 v = __half22float2(hp[(size_t)n * 64]);
        ax += v.x; ay += v.y;
    }
    float c = fmaxf((float)(e - s), 1.0f);
    float mx = ax / c, my = ay / c;
    float mu = wave_reduce_sum(mx + my) * (1.0f / 128.0f);
    float dx = mx - mu, dy = my - mu;
    float var = wave_reduce_sum(dx * dx + dy * dy) * (1.0f / 128.0f);
    float r = rsqrtf(var + 1e-5f);
    float2 wl = *(const float2*)(Wl + lane * 2);
    float o = wave_reduce_sum(dx * r * wl.x + dy * r * wl.y);
    if (lane == 0) out[g] = o + bl[0];
}

extern "C" void kernel_launch(void* const* d_in, const int* in_sizes, int n_in,
                              void* d_out, int out_size, void* d_ws, size_t ws_size,
                              hipStream_t stream) {
    const float* x  = (const float*)d_in[0];
    const int* ei   = (const int*)d_in[1];      // [2][E]
    const int* batch = (const int*)d_in[2];
    const float* Ws[5] = {(const float*)d_in[3], (const float*)d_in[5],
                          (const float*)d_in[7], (const float*)d_in[9],
                          (const float*)d_in[11]};
    const float* bs[5] = {(const float*)d_in[4], (const float*)d_in[6],
                          (const float*)d_in[8], (const float*)d_in[10],
                          (const float*)d_in[12]};
    const float* beta1 = (const float*)d_in[13];
    const float* beta2 = (const float*)d_in[14];
    const float* Wl = (const float*)d_in[15];
    const float* bl = (const float*)d_in[16];
    float* out = (float*)d_out;

    int N = in_sizes[0] / 128;
    int E = in_sizes[1] / 2;
    int G = out_size;

    char* ws = (char*)d_ws;
    size_t off = 0;
    auto alloc = [&](size_t bytes) -> void* {
        void* p = ws + off;
        off = (off + bytes + 255) & ~(size_t)255;
        return p;
    };
    float*  agg  = (float*)alloc((size_t)N * 128 * 4);
    __half* hA   = (__half*)alloc((size_t)N * 128 * 2);
    __half* hB   = (__half*)alloc((size_t)N * 128 * 2);
    int*   deg   = (int*)alloc((size_t)N * 4);
    int*   offs  = (int*)alloc((size_t)(N + 1) * 4);
    int*   cursor= (int*)alloc((size_t)N * 4);
    int*   csr   = (int*)alloc((size_t)(E + N) * 4);
    float* dis   = (float*)alloc((size_t)N * 4);
    float* invn  = (float*)alloc((size_t)N * 4);
    float* invn2 = (float*)alloc((size_t)N * 4);
    int nb = (N + 1023) / 1024;
    int*   part  = (int*)alloc((size_t)nb * 4);
    int*   gst   = (int*)alloc((size_t)(G + 1) * 4);

    // CSR build + x cast
    k_init_deg<<<(N + 255) / 256, 256, 0, stream>>>(deg, N);
    k_count<<<(E + 255) / 256, 256, 0, stream>>>(ei + E, deg, E);
    k_dis<<<(N + 255) / 256, 256, 0, stream>>>(deg, dis, N);
    k_scan1<<<nb, 256, 0, stream>>>(deg, part, N);
    k_scan2<<<1, 64, 0, stream>>>(part, nb, offs, N);
    k_scan3<<<nb, 256, 0, stream>>>(deg, part, offs, N);
    hipMemsetAsync(cursor, 0, (size_t)N * 4, stream);
    k_fill<<<(E + N + 255) / 256, 256, 0, stream>>>(ei, E, N, offs, cursor, csr);
    k_gstart<<<(G + 1 + 255) / 256, 256, 0, stream>>>(batch, N, gst, G);
    k_cast<<<(N * 64 + 255) / 256, 256, 0, stream>>>(x, hA, N * 64);

    int aggBlocks = (N + 3) / 4;
    int gemmBlocks = (N + 31) / 32;

    // 5 GCN layers; layer 5's GEMM epilogue produces invn of its fp32 output
    const __half* hin = hA;
    __half* hout = hB;
    for (int l = 0; l < 5; ++l) {
        k_gcn_agg<<<aggBlocks, 256, 0, stream>>>(hin, csr, offs, dis, agg, N);
        k_gemm_bias_tanh<<<gemmBlocks, 256, 0, stream>>>(
            agg, Ws[l], bs[l], hout, N, (l == 4) ? invn : nullptr);
        const __half* t = hin; hin = hout; hout = (__half*)t;
    }
    // after loop: hin = h5 (hB), hout = hA
    k_agnn<<<aggBlocks, 256, 0, stream>>>(hin, csr, offs, invn, beta1, hout, N, invn2);
    k_agnn<<<aggBlocks, 256, 0, stream>>>(hout, csr, offs, invn2, beta2, (__half*)hin, N, nullptr);
    k_pool<<<(G + 3) / 4, 256, 0, stream>>>(hin, gst, Wl, bl, out, G);
}

// Round 4
// 1039.653 us; speedup vs baseline: 1.8077x; 1.0571x over previous
//
#include <hip/hip_runtime.h>
#include <hip/hip_fp16.h>
#include <math.h>

__device__ __forceinline__ void unpack8(uint4 u, float* f) {
    union { uint4 u; __half2 h2[4]; } U; U.u = u;
    float2 a = __half22float2(U.h2[0]);
    float2 b = __half22float2(U.h2[1]);
    float2 c = __half22float2(U.h2[2]);
    float2 d = __half22float2(U.h2[3]);
    f[0] = a.x; f[1] = a.y; f[2] = b.x; f[3] = b.y;
    f[4] = c.x; f[5] = c.y; f[6] = d.x; f[7] = d.y;
}

// ---------- preprocessing ----------
__global__ void k_init_deg(int* deg, int N) {
    int i = blockIdx.x * blockDim.x + threadIdx.x;
    if (i < N) deg[i] = 1;  // self loop
}

__global__ void k_count(const int* __restrict__ dst, int* deg, int E) {
    int i = blockIdx.x * blockDim.x + threadIdx.x;
    if (i < E) atomicAdd(&deg[dst[i]], 1);
}

__global__ void k_dis(const int* __restrict__ deg, float* dis, int N) {
    int i = blockIdx.x * blockDim.x + threadIdx.x;
    if (i < N) dis[i] = rsqrtf((float)deg[i]);  // deg >= 1 always
}

// exclusive scan of deg[0..N) -> offs[0..N], offs[N] = total
__global__ void k_scan1(const int* __restrict__ deg, int* part, int N) {
    int base = blockIdx.x * 1024;
    int tid = threadIdx.x;
    int s = 0;
#pragma unroll
    for (int j = 0; j < 4; ++j) {
        int idx = base + tid * 4 + j;
        if (idx < N) s += deg[idx];
    }
    __shared__ int sm[256];
    sm[tid] = s;
    __syncthreads();
    for (int off = 128; off > 0; off >>= 1) {
        if (tid < off) sm[tid] += sm[tid + off];
        __syncthreads();
    }
    if (tid == 0) part[blockIdx.x] = sm[0];
}

__global__ void k_scan2(int* part, int nb, int* offs, int N) {
    if (blockIdx.x == 0 && threadIdx.x == 0) {
        int run = 0;
        for (int b = 0; b < nb; ++b) { int t = part[b]; part[b] = run; run += t; }
        offs[N] = run;
    }
}

__global__ void k_scan3(const int* __restrict__ deg, const int* __restrict__ part,
                        int* offs, int N) {
    __shared__ int sm[256];
    int base = blockIdx.x * 1024;
    int tid = threadIdx.x;
    int a[4];
    int s = 0;
#pragma unroll
    for (int j = 0; j < 4; ++j) {
        int idx = base + tid * 4 + j;
        a[j] = (idx < N) ? deg[idx] : 0;
        s += a[j];
    }
    sm[tid] = s;
    __syncthreads();
    for (int off = 1; off < 256; off <<= 1) {
        int v = (tid >= off) ? sm[tid - off] : 0;
        __syncthreads();
        sm[tid] += v;
        __syncthreads();
    }
    int excl = sm[tid] - s + part[blockIdx.x];
#pragma unroll
    for (int j = 0; j < 4; ++j) {
        int idx = base + tid * 4 + j;
        if (idx < N) offs[idx] = excl;
        excl += a[j];
    }
}

__global__ void k_fill(const int* __restrict__ ei, int E, int N,
                       const int* __restrict__ offs, const float* __restrict__ dis,
                       int* cursor, int* csr, float* wedge) {
    int i = blockIdx.x * blockDim.x + threadIdx.x;
    if (i >= E + N) return;
    int s, d;
    if (i < E) { s = ei[i]; d = ei[E + i]; }
    else { s = d = i - E; }
    int p = offs[d] + atomicAdd(&cursor[d], 1);
    csr[p] = s;
    wedge[p] = dis[s];   // per-edge GCN weight factor, reused by all 5 layers
}

__global__ void k_gstart(const int* __restrict__ batch, int N, int* gstart, int G) {
    int g = blockIdx.x * blockDim.x + threadIdx.x;
    if (g > G) return;
    int lo = 0, hi = N;
    while (lo < hi) {
        int mid = (lo + hi) >> 1;
        if (batch[mid] < g) lo = mid + 1; else hi = mid;
    }
    gstart[g] = lo;
}

// ---------- f32 -> fp16 cast (x pre-pass) ----------
__global__ __launch_bounds__(256) void k_cast(
    const float* __restrict__ x, __half* __restrict__ hx, int npairs)
{
    int i = blockIdx.x * blockDim.x + threadIdx.x;
    if (i >= npairs) return;
    float2 v = ((const float2*)x)[i];
    ((__half2*)hx)[i] = __floats2half2_rn(v.x, v.y);
}

// ---------- GCN aggregation: 16 lanes/node, 8 feats/lane ----------
__global__ __launch_bounds__(256) void k_gcn_agg(
    const __half* __restrict__ h, const int* __restrict__ csr,
    const float* __restrict__ wedge, const int* __restrict__ offs,
    const float* __restrict__ dis, float* __restrict__ agg, int N)
{
    int node = (blockIdx.x * blockDim.x + threadIdx.x) >> 4;
    int l = threadIdx.x & 15;
    if (node >= N) return;
    int j0 = offs[node], j1 = offs[node + 1];
    float dd = dis[node];
    const uint4* hp = (const uint4*)h + l;   // row stride: 16 uint4
    float acc[8] = {0.f, 0.f, 0.f, 0.f, 0.f, 0.f, 0.f, 0.f};
    int j = j0;
    for (; j + 4 <= j1; j += 4) {
        int s0 = csr[j + 0], s1 = csr[j + 1], s2 = csr[j + 2], s3 = csr[j + 3];
        float w0 = wedge[j + 0], w1 = wedge[j + 1], w2 = wedge[j + 2], w3 = wedge[j + 3];
        uint4 u0 = hp[(size_t)s0 * 16];
        uint4 u1 = hp[(size_t)s1 * 16];
        uint4 u2 = hp[(size_t)s2 * 16];
        uint4 u3 = hp[(size_t)s3 * 16];
        float f0[8], f1[8], f2[8], f3[8];
        unpack8(u0, f0); unpack8(u1, f1); unpack8(u2, f2); unpack8(u3, f3);
#pragma unroll
        for (int i = 0; i < 8; ++i)
            acc[i] += w0 * f0[i] + w1 * f1[i] + w2 * f2[i] + w3 * f3[i];
    }
    for (; j < j1; ++j) {
        int s = csr[j];
        float w = wedge[j];
        uint4 u = hp[(size_t)s * 16];
        float f[8]; unpack8(u, f);
#pragma unroll
        for (int i = 0; i < 8; ++i) acc[i] += w * f[i];
    }
    float* op = agg + (size_t)node * 128 + l * 8;
    *(float4*)op       = make_float4(dd * acc[0], dd * acc[1], dd * acc[2], dd * acc[3]);
    *(float4*)(op + 4) = make_float4(dd * acc[4], dd * acc[5], dd * acc[6], dd * acc[7]);
}

// ---------- fused out(fp16) = tanh(in @ W + b); optional invnorm epilogue ----------
__global__ __launch_bounds__(256) void k_gemm_bias_tanh(
    const float* __restrict__ in, const float* __restrict__ W,
    const float* __restrict__ bias, __half* __restrict__ out, int nrows,
    float* __restrict__ invn_out)
{
    __shared__ float Wl[64][128];
    __shared__ float inT[128][36];
    int tid = threadIdx.x;
    int row0 = blockIdx.x * 32;

    for (int t = tid; t < 1024; t += 256) {
        int r = t >> 5, k4 = t & 31;
        int row = row0 + r;
        float4 v = make_float4(0.f, 0.f, 0.f, 0.f);
        if (row < nrows) v = *(const float4*)(in + (size_t)row * 128 + k4 * 4);
        inT[k4 * 4 + 0][r] = v.x;
        inT[k4 * 4 + 1][r] = v.y;
        inT[k4 * 4 + 2][r] = v.z;
        inT[k4 * 4 + 3][r] = v.w;
    }

    int cg = tid & 31;
    int rg = tid >> 5;
    float acc[4][4] = {};

    for (int kt = 0; kt < 2; ++kt) {
        __syncthreads();
        for (int t = tid; t < 2048; t += 256) {
            int k = t >> 5, c4 = t & 31;
            *(float4*)&Wl[k][c4 * 4] =
                *(const float4*)(W + (size_t)(kt * 64 + k) * 128 + c4 * 4);
        }
        __syncthreads();
#pragma unroll 4
        for (int k = 0; k < 64; ++k) {
            float4 a = *(const float4*)&inT[kt * 64 + k][rg * 4];
            float4 wv = *(const float4*)&Wl[k][cg * 4];
            float av[4] = {a.x, a.y, a.z, a.w};
            float wvv[4] = {wv.x, wv.y, wv.z, wv.w};
#pragma unroll
            for (int i = 0; i < 4; ++i)
#pragma unroll
                for (int j = 0; j < 4; ++j)
                    acc[i][j] += av[i] * wvv[j];
        }
    }

    float4 bb = *(const float4*)(bias + cg * 4);
    float bv[4] = {bb.x, bb.y, bb.z, bb.w};
    float sq[4];
#pragma unroll
    for (int i = 0; i < 4; ++i) {
        int row = row0 + rg * 4 + i;
        float ox = tanhf(acc[i][0] + bv[0]);
        float oy = tanhf(acc[i][1] + bv[1]);
        float oz = tanhf(acc[i][2] + bv[2]);
        float ow = tanhf(acc[i][3] + bv[3]);
        sq[i] = ox * ox + oy * oy + oz * oz + ow * ow;
        if (row < nrows) {
            union { __half2 h[2]; uint2 u; } pk;
            pk.h[0] = __floats2half2_rn(ox, oy);
            pk.h[1] = __floats2half2_rn(oz, ow);
            *(uint2*)(out + (size_t)row * 128 + cg * 4) = pk.u;
        }
    }
    if (invn_out) {
#pragma unroll
        for (int i = 0; i < 4; ++i) {
#pragma unroll
            for (int off = 16; off > 0; off >>= 1) sq[i] += __shfl_xor(sq[i], off, 64);
            int row = row0 + rg * 4 + i;
            if (cg == 0 && row < nrows)
                invn_out[row] = 1.0f / fmaxf(sqrtf(sq[i]), 1e-12f);
        }
    }
}

// ---------- AGNN layer: 16 lanes/node, shift-free softmax, fused tanh ----------
__global__ __launch_bounds__(256) void k_agnn(
    const __half* __restrict__ h, const int* __restrict__ csr,
    const int* __restrict__ offs, const float* __restrict__ invn,
    const float* __restrict__ beta_p, __half* __restrict__ out, int N,
    float* __restrict__ invn_out)
{
    int node = (blockIdx.x * blockDim.x + threadIdx.x) >> 4;
    int l = threadIdx.x & 15;
    if (node >= N) return;
    int j0 = offs[node], j1 = offs[node + 1];
    const uint4* hp = (const uint4*)h + l;
    float hd[8]; unpack8(hp[(size_t)node * 16], hd);
    float bi = beta_p[0] * invn[node];
    float denom = 0.f;
    float acc[8] = {0.f, 0.f, 0.f, 0.f, 0.f, 0.f, 0.f, 0.f};
    int j = j0;
    for (; j + 2 <= j1; j += 2) {
        int s0 = csr[j], s1 = csr[j + 1];
        float in0 = invn[s0], in1 = invn[s1];
        uint4 u0 = hp[(size_t)s0 * 16];
        uint4 u1 = hp[(size_t)s1 * 16];
        float f0[8], f1[8];
        unpack8(u0, f0); unpack8(u1, f1);
        float d0 = 0.f, d1 = 0.f;
#pragma unroll
        for (int i = 0; i < 8; ++i) { d0 += f0[i] * hd[i]; d1 += f1[i] * hd[i]; }
#pragma unroll
        for (int off = 1; off < 16; off <<= 1) {
            d0 += __shfl_xor(d0, off, 64);
            d1 += __shfl_xor(d1, off, 64);
        }
        float p0 = __expf(bi * in0 * d0);
        float p1 = __expf(bi * in1 * d1);
        denom += p0 + p1;
#pragma unroll
        for (int i = 0; i < 8; ++i) acc[i] += p0 * f0[i] + p1 * f1[i];
    }
    for (; j < j1; ++j) {
        int s = csr[j];
        float ins = invn[s];
        uint4 u = hp[(size_t)s * 16];
        float f[8]; unpack8(u, f);
        float d = 0.f;
#pragma unroll
        for (int i = 0; i < 8; ++i) d += f[i] * hd[i];
#pragma unroll
        for (int off = 1; off < 16; off <<= 1) d += __shfl_xor(d, off, 64);
        float p = __expf(bi * ins * d);
        denom += p;
#pragma unroll
        for (int i = 0; i < 8; ++i) acc[i] += p * f[i];
    }
    float inv = 1.0f / denom;
    float o[8];
#pragma unroll
    for (int i = 0; i < 8; ++i) o[i] = tanhf(acc[i] * inv);
    union { uint4 u; __half2 h2[4]; } P;
    P.h2[0] = __floats2half2_rn(o[0], o[1]);
    P.h2[1] = __floats2half2_rn(o[2], o[3]);
    P.h2[2] = __floats2half2_rn(o[4], o[5]);
    P.h2[3] = __floats2half2_rn(o[6], o[7]);
    ((uint4*)out)[(size_t)node * 16 + l] = P.u;
    if (invn_out) {
        float s2 = 0.f;
#pragma unroll
        for (int i = 0; i < 8; ++i) s2 += o[i] * o[i];
#pragma unroll
        for (int off = 1; off < 16; off <<= 1) s2 += __shfl_xor(s2, off, 64);
        if (l == 0) invn_out[node] = 1.0f / fmaxf(sqrtf(s2), 1e-12f);
    }
}

// ---------- per-graph mean pool + layernorm + final linear (16 lanes/graph) ----------
__global__ __launch_bounds__(256) void k_pool(
    const __half* __restrict__ h, const int* __restrict__ gstart,
    const float* __restrict__ Wl, const float* __restrict__ bl,
    float* __restrict__ out, int G)
{
    int g = (blockIdx.x * blockDim.x + threadIdx.x) >> 4;
    int l = threadIdx.x & 15;
    if (g >= G) return;
    int s = gstart[g], e = gstart[g + 1];
    const uint4* hp = (const uint4*)h + l;
    float acc[8] = {0.f, 0.f, 0.f, 0.f, 0.f, 0.f, 0.f, 0.f};
    for (int n = s; n < e; ++n) {
        float f[8]; unpack8(hp[(size_t)n * 16], f);
#pragma unroll
        for (int i = 0; i < 8; ++i) acc[i] += f[i];
    }
    float inv = 1.0f / fmaxf((float)(e - s), 1.0f);
#pragma unroll
    for (int i = 0; i < 8; ++i) acc[i] *= inv;
    float part = 0.f;
#pragma unroll
    for (int i = 0; i < 8; ++i) part += acc[i];
#pragma unroll
    for (int off = 1; off < 16; off <<= 1) part += __shfl_xor(part, off, 64);
    float mu = part * (1.0f / 128.0f);
    float vpart = 0.f;
#pragma unroll
    for (int i = 0; i < 8; ++i) { float d = acc[i] - mu; vpart += d * d; }
#pragma unroll
    for (int off = 1; off < 16; off <<= 1) vpart += __shfl_xor(vpart, off, 64);
    float r = rsqrtf(vpart * (1.0f / 128.0f) + 1e-5f);
    float4 w0 = *(const float4*)(Wl + l * 8);
    float4 w1 = *(const float4*)(Wl + l * 8 + 4);
    float wv[8] = {w0.x, w0.y, w0.z, w0.w, w1.x, w1.y, w1.z, w1.w};
    float dot = 0.f;
#pragma unroll
    for (int i = 0; i < 8; ++i) dot += (acc[i] - mu) * r * wv[i];
#pragma unroll
    for (int off = 1; off < 16; off <<= 1) dot += __shfl_xor(dot, off, 64);
    if (l == 0) out[g] = dot + bl[0];
}

extern "C" void kernel_launch(void* const* d_in, const int* in_sizes, int n_in,
                              void* d_out, int out_size, void* d_ws, size_t ws_size,
                              hipStream_t stream) {
    const float* x  = (const float*)d_in[0];
    const int* ei   = (const int*)d_in[1];      // [2][E]
    const int* batch = (const int*)d_in[2];
    const float* Ws[5] = {(const float*)d_in[3], (const float*)d_in[5],
                          (const float*)d_in[7], (const float*)d_in[9],
                          (const float*)d_in[11]};
    const float* bs[5] = {(const float*)d_in[4], (const float*)d_in[6],
                          (const float*)d_in[8], (const float*)d_in[10],
                          (const float*)d_in[12]};
    const float* beta1 = (const float*)d_in[13];
    const float* beta2 = (const float*)d_in[14];
    const float* Wl = (const float*)d_in[15];
    const float* bl = (const float*)d_in[16];
    float* out = (float*)d_out;

    int N = in_sizes[0] / 128;
    int E = in_sizes[1] / 2;
    int G = out_size;

    char* ws = (char*)d_ws;
    size_t off = 0;
    auto alloc = [&](size_t bytes) -> void* {
        void* p = ws + off;
        off = (off + bytes + 255) & ~(size_t)255;
        return p;
    };
    float*  agg  = (float*)alloc((size_t)N * 128 * 4);
    __half* hA   = (__half*)alloc((size_t)N * 128 * 2);
    __half* hB   = (__half*)alloc((size_t)N * 128 * 2);
    int*   deg   = (int*)alloc((size_t)N * 4);
    int*   offs  = (int*)alloc((size_t)(N + 1) * 4);
    int*   cursor= (int*)alloc((size_t)N * 4);
    int*   csr   = (int*)alloc((size_t)(E + N) * 4);
    float* wedge = (float*)alloc((size_t)(E + N) * 4);
    float* dis   = (float*)alloc((size_t)N * 4);
    float* invn  = (float*)alloc((size_t)N * 4);
    float* invn2 = (float*)alloc((size_t)N * 4);
    int nb = (N + 1023) / 1024;
    int*   part  = (int*)alloc((size_t)nb * 4);
    int*   gst   = (int*)alloc((size_t)(G + 1) * 4);

    // CSR build + x cast
    k_init_deg<<<(N + 255) / 256, 256, 0, stream>>>(deg, N);
    k_count<<<(E + 255) / 256, 256, 0, stream>>>(ei + E, deg, E);
    k_dis<<<(N + 255) / 256, 256, 0, stream>>>(deg, dis, N);
    k_scan1<<<nb, 256, 0, stream>>>(deg, part, N);
    k_scan2<<<1, 64, 0, stream>>>(part, nb, offs, N);
    k_scan3<<<nb, 256, 0, stream>>>(deg, part, offs, N);
    hipMemsetAsync(cursor, 0, (size_t)N * 4, stream);
    k_fill<<<(E + N + 255) / 256, 256, 0, stream>>>(ei, E, N, offs, dis, cursor, csr, wedge);
    k_gstart<<<(G + 1 + 255) / 256, 256, 0, stream>>>(batch, N, gst, G);
    k_cast<<<(N * 64 + 255) / 256, 256, 0, stream>>>(x, hA, N * 64);

    int aggBlocks = (N + 15) / 16;   // 16 nodes per 256-thread block
    int gemmBlocks = (N + 31) / 32;

    // 5 GCN layers; layer 5's GEMM epilogue produces invn of its output
    const __half* hin = hA;
    __half* hout = hB;
    for (int l = 0; l < 5; ++l) {
        k_gcn_agg<<<aggBlocks, 256, 0, stream>>>(hin, csr, wedge, offs, dis, agg, N);
        k_gemm_bias_tanh<<<gemmBlocks, 256, 0, stream>>>(
            agg, Ws[l], bs[l], hout, N, (l == 4) ? invn : nullptr);
        const __half* t = hin; hin = hout; hout = (__half*)t;
    }
    // after loop: hin = h5 (hB), hout = hA
    k_agnn<<<aggBlocks, 256, 0, stream>>>(hin, csr, offs, invn, beta1, hout, N, invn2);
    k_agnn<<<aggBlocks, 256, 0, stream>>>(hout, csr, offs, invn2, beta2, (__half*)hin, N, nullptr);
    k_pool<<<(G + 15) / 16, 256, 0, stream>>>(hin, gst, Wl, bl, out, G);
}